// Round 6
// baseline (196.463 us; speedup 1.0000x reference)
//
#include <hip/hip_runtime.h>
#include <stdint.h>

#define LOG2E       1.4426950408889634f
#define INV_SQRT32  0.17677669529663687f

using bf16x8 = __attribute__((ext_vector_type(8))) short;
using f32x4  = __attribute__((ext_vector_type(4))) float;

__device__ __forceinline__ unsigned short f2bf(float f) {
  union { float f; uint32_t u; } v; v.f = f;
  uint32_t r = v.u + 0x7fffu + ((v.u >> 16) & 1u);   // RNE
  return (unsigned short)(r >> 16);
}

typedef const __attribute__((address_space(1))) void* gas_ptr;
typedef __attribute__((address_space(3))) void*       las_ptr;
__device__ __forceinline__ void load_lds16(const void* g, void* l) {
  // wave-uniform LDS base; HW scatters lane i -> base + i*16
  __builtin_amdgcn_global_load_lds((gas_ptr)g, (las_ptr)l, 16, 0, 0);
}

// ---------- kernel 1 (merged): blocks [0,4096): x fp32 [b][c][s] -> Xt bf16 [b][s][c]
//                               blocks [4096,4288): W fp32 -> Wcat bf16 [768][256] + bias
__global__ __launch_bounds__(256) void pre(
    const float* __restrict__ x, unsigned short* __restrict__ xt,
    const float* __restrict__ wq, const float* __restrict__ bq,
    const float* __restrict__ wk, const float* __restrict__ bk,
    const float* __restrict__ wv, const float* __restrict__ bv,
    unsigned short* __restrict__ Wcat, float* __restrict__ biasc) {
  __shared__ float tile[64 * 65];
  int bid = blockIdx.x;
  int t = threadIdx.x;
  if (bid < 4096) {
    // transpose_x: s-tile = bid&63, c-tile = (bid>>6)&3, b = bid>>8
    int b = bid >> 8;
    int s0 = (bid & 63) * 64, c0 = ((bid >> 6) & 3) * 64;
    int sl = t & 63, g = t >> 6;
    const float* xp = x + ((size_t)(b * 256 + c0)) * 4096 + s0 + sl;
#pragma unroll
    for (int ii = 0; ii < 16; ++ii) {
      int cl = g * 16 + ii;
      tile[cl * 65 + sl] = xp[(size_t)cl * 4096];
    }
    __syncthreads();
#pragma unroll
    for (int it = 0; it < 2; ++it) {
      int idx = it * 256 + t;
      int s_loc = idx >> 3, cb = (idx & 7) * 8;
      unsigned short ov[8];
#pragma unroll
      for (int j = 0; j < 8; ++j) ov[j] = f2bf(tile[(cb + j) * 65 + s_loc]);
      *(uint4*)&xt[((size_t)(b * 4096 + s0 + s_loc)) * 256 + c0 + cb] = *(uint4*)ov;
    }
  } else {
    int cb = bid - 4096;
    int idx = (cb * 256 + t) * 4;   // flat into 768*256
    int p = idx >> 16;
    int rem = idx & 0xffff;
    const float* src = (p == 0) ? wq : (p == 1) ? wk : wv;
    float4 v = *(const float4*)(src + rem);
    ushort4 o;
    o.x = f2bf(v.x); o.y = f2bf(v.y); o.z = f2bf(v.z); o.w = f2bf(v.w);
    *(ushort4*)(Wcat + idx) = o;
    if (cb < 3) {
      const float* sb = (cb == 0) ? bq : (cb == 1) ? bk : bv;
      biasc[cb * 256 + t] = sb[t];
    }
  }
}

// ---------- kernel 2: qkv[b][768][4096] bf16 = Wcat[768][256] * Xt[b][4096][256]^T + bias
// v5 (verified best): depth-2 counted-vmcnt pipeline + swapped-operand MFMA +
//     LDS-staged epilogue reusing As/Bs -> 256B-coalesced stores.
__global__ __launch_bounds__(256) void gemm_qkv(
    const unsigned short* __restrict__ Wc, const float* __restrict__ biasc,
    const unsigned short* __restrict__ Xt, unsigned short* __restrict__ qkv) {
  __shared__ unsigned short sh[16384];   // As[2][4096] @0 | Bs[2][4096] @8192; reused as C[128][128]
  int blk = blockIdx.x;
  int b = blk / 192;
  int rest = blk - b * 192;
  int mt = rest >> 5, nt = rest & 31;
  int m0 = mt * 128, n0 = nt * 128;
  int tid = threadIdx.x;
  int lane = tid & 63, wave = tid >> 6;
  int quad = lane >> 4, rt = lane & 15;
  int wm = wave >> 1, wn = wave & 1;

  f32x4 acc[4][4];
#pragma unroll
  for (int i = 0; i < 4; ++i)
#pragma unroll
    for (int j = 0; j < 4; ++j) acc[i][j] = (f32x4){0.f, 0.f, 0.f, 0.f};

  int lr = lane >> 2;
  int sl_src = (lane & 3) ^ ((lane >> 3) & 3);
  const unsigned short* gA0 = Wc + (size_t)(m0 + wave * 32 + lr) * 256 + sl_src * 8;
  const unsigned short* gA1 = gA0 + 16 * 256;
  const unsigned short* gB0 = Xt + ((size_t)b * 4096 + n0 + wave * 32 + lr) * 256 + sl_src * 8;
  const unsigned short* gB1 = gB0 + 16 * 256;

#define STAGE(bufi, ko)                                                     \
  do {                                                                      \
    load_lds16(gA0 + (ko), &sh[(bufi) * 4096 + wave * 1024]);               \
    load_lds16(gA1 + (ko), &sh[(bufi) * 4096 + wave * 1024 + 512]);         \
    load_lds16(gB0 + (ko), &sh[8192 + (bufi) * 4096 + wave * 1024]);        \
    load_lds16(gB1 + (ko), &sh[8192 + (bufi) * 4096 + wave * 1024 + 512]);  \
  } while (0)

  int rsw = (quad ^ ((rt >> 1) & 3)) * 8;   // swizzled read slot (elements)

  STAGE(0, 0);
  STAGE(1, 32);

#define KSTEP(kc, WAITN)                                                      \
  do {                                                                        \
    asm volatile("s_waitcnt vmcnt(" #WAITN ")" ::: "memory");                 \
    __builtin_amdgcn_s_barrier();                                             \
    __builtin_amdgcn_sched_barrier(0);                                        \
    const unsigned short* A_ = &sh[((kc) & 1) * 4096];                        \
    const unsigned short* B_ = &sh[8192 + ((kc) & 1) * 4096];                 \
    bf16x8 af[4], bfr[4];                                                     \
    _Pragma("unroll")                                                         \
    for (int mi = 0; mi < 4; ++mi)                                            \
      af[mi] = *(const bf16x8*)&A_[(wm * 64 + mi * 16 + rt) * 32 + rsw];      \
    _Pragma("unroll")                                                         \
    for (int ni = 0; ni < 4; ++ni)                                            \
      bfr[ni] = *(const bf16x8*)&B_[(wn * 64 + ni * 16 + rt) * 32 + rsw];     \
    _Pragma("unroll")                                                         \
    for (int mi = 0; mi < 4; ++mi)                                            \
      _Pragma("unroll")                                                       \
      for (int ni = 0; ni < 4; ++ni)                                          \
        acc[mi][ni] = __builtin_amdgcn_mfma_f32_16x16x32_bf16(bfr[ni], af[mi], acc[mi][ni], 0, 0, 0); \
    __builtin_amdgcn_sched_barrier(0);                                        \
    __builtin_amdgcn_s_barrier();                                             \
    if ((kc) + 2 < 8) STAGE((kc) & 1, ((kc) + 2) * 32);                       \
  } while (0)

  KSTEP(0, 4);
  KSTEP(1, 4);
  KSTEP(2, 4);
  KSTEP(3, 4);
  KSTEP(4, 4);
  KSTEP(5, 4);
  KSTEP(6, 4);
  KSTEP(7, 0);
#undef KSTEP
#undef STAGE

  unsigned short* C = sh;
  size_t obase = (size_t)b * 768;
#pragma unroll
  for (int mi = 0; mi < 4; ++mi) {
    int o_loc = wm * 64 + mi * 16 + rt;
    float bo = biasc[m0 + o_loc];
#pragma unroll
    for (int ni = 0; ni < 4; ++ni) {
      int g0 = wn * 8 + ni * 2 + (quad >> 1);
      int pg = g0 ^ (o_loc & 7);
      ushort4 st;
      st.x = f2bf(acc[mi][ni][0] + bo);
      st.y = f2bf(acc[mi][ni][1] + bo);
      st.z = f2bf(acc[mi][ni][2] + bo);
      st.w = f2bf(acc[mi][ni][3] + bo);
      *(ushort4*)&C[o_loc * 128 + pg * 8 + (quad & 1) * 4] = st;
    }
  }
  __syncthreads();
#pragma unroll
  for (int i = 0; i < 8; ++i) {
    int idx = i * 256 + tid;
    int row = idx >> 4, g = idx & 15;
    int pg = g ^ (row & 7);
    bf16x8 v = *(const bf16x8*)&C[row * 128 + pg * 8];
    *(bf16x8*)&qkv[(obase + m0 + row) * 4096 + n0 + g * 8] = v;
  }
}

// ---------- kernel 3: per-(b, o) 64x64 attention, v3: in-register softmax, 3 barriers
// S = Q K^T (contract w), softmax over g (shfl_xor over rt + LDS cross-wave), O = P V
// LDS (un-overlaid): Qs/Ks/Vt/Ps 9216 each + redm/reds 512 each = 37888 B (4 blocks/CU)
__global__ __launch_bounds__(256) void attn(const unsigned short* __restrict__ qkv,
                                            float* __restrict__ out) {
  __shared__ unsigned short Qs[64 * 72];
  __shared__ unsigned short Ks[64 * 72];
  __shared__ unsigned short Vt[64 * 72];
  __shared__ unsigned short Ps[64 * 72];
  __shared__ float redm[128];   // [wn][h] partial rowmax
  __shared__ float reds[128];   // [wn][h] partial rowsum

  int blk = blockIdx.x;
  int b = blk >> 8, o = blk & 255;
  int t = threadIdx.x;
  size_t base = ((size_t)b * 768 + o) * 4096;
  const unsigned short* qg = qkv + base;
  const unsigned short* kg = qkv + base + (size_t)256 * 4096;
  const unsigned short* vg = qkv + base + (size_t)512 * 4096;

  // --- stage Q,K as [h][w]; V transposed as Vt[w][g] (2 w x 8 g per thread, 4B loads)
  {
    int h = t >> 2, w0 = (t & 3) * 16;
    const uint4* qp = (const uint4*)(qg + h * 64 + w0);
    const uint4* kp = (const uint4*)(kg + h * 64 + w0);
    uint4 q0 = qp[0], q1 = qp[1];
    uint4 k0 = kp[0], k1 = kp[1];
    *(uint4*)&Qs[h * 72 + w0]     = q0;
    *(uint4*)&Qs[h * 72 + w0 + 8] = q1;
    *(uint4*)&Ks[h * 72 + w0]     = k0;
    *(uint4*)&Ks[h * 72 + w0 + 8] = k1;

    int vw = (t & 31) * 2, vg0 = (t >> 5) * 8;
    unsigned short lo8[8], hi8[8];
#pragma unroll
    for (int j = 0; j < 8; ++j) {
      uint32_t v2 = *(const uint32_t*)&vg[(size_t)(vg0 + j) * 64 + vw];
      lo8[j] = (unsigned short)(v2 & 0xffffu);
      hi8[j] = (unsigned short)(v2 >> 16);
    }
    *(uint4*)&Vt[vw * 72 + vg0]       = *(uint4*)lo8;
    *(uint4*)&Vt[(vw + 1) * 72 + vg0] = *(uint4*)hi8;
  }
  __syncthreads();   // barrier 1: Qs/Ks/Vt staged

  int lane = t & 63, wave = t >> 6;
  int rt = lane & 15, quad = lane >> 4;
  int wm = wave >> 1, wn = wave & 1;

  // --- S = Q K^T via MFMA: 2x2 tiles of 16x16 per wave, K=64 (2 steps)
  f32x4 accs[2][2];
#pragma unroll
  for (int i = 0; i < 2; ++i)
#pragma unroll
    for (int j = 0; j < 2; ++j) accs[i][j] = (f32x4){0.f, 0.f, 0.f, 0.f};
#pragma unroll
  for (int ks = 0; ks < 2; ++ks) {
    int kk = ks * 32 + quad * 8;
    bf16x8 a0 = *(const bf16x8*)&Qs[(wm * 32 + rt) * 72 + kk];
    bf16x8 a1 = *(const bf16x8*)&Qs[(wm * 32 + 16 + rt) * 72 + kk];
    bf16x8 b0 = *(const bf16x8*)&Ks[(wn * 32 + rt) * 72 + kk];
    bf16x8 b1 = *(const bf16x8*)&Ks[(wn * 32 + 16 + rt) * 72 + kk];
    accs[0][0] = __builtin_amdgcn_mfma_f32_16x16x32_bf16(a0, b0, accs[0][0], 0, 0, 0);
    accs[0][1] = __builtin_amdgcn_mfma_f32_16x16x32_bf16(a0, b1, accs[0][1], 0, 0, 0);
    accs[1][0] = __builtin_amdgcn_mfma_f32_16x16x32_bf16(a1, b0, accs[1][0], 0, 0, 0);
    accs[1][1] = __builtin_amdgcn_mfma_f32_16x16x32_bf16(a1, b1, accs[1][1], 0, 0, 0);
  }

  // D-layout: lane holds S[h][g], h = wm*32+tm*16+quad*4+r, g = wn*32+tn*16+rt.
  // --- row-max over this wave's 32 g: per-lane over tn, then shfl_xor over rt bits
  float pm[2][4];
#pragma unroll
  for (int tm = 0; tm < 2; ++tm)
#pragma unroll
    for (int r = 0; r < 4; ++r) {
      float m = fmaxf(accs[tm][0][r], accs[tm][1][r]);
      m = fmaxf(m, __shfl_xor(m, 1));
      m = fmaxf(m, __shfl_xor(m, 2));
      m = fmaxf(m, __shfl_xor(m, 4));
      m = fmaxf(m, __shfl_xor(m, 8));
      pm[tm][r] = m;
    }
  if (rt == 0) {
#pragma unroll
    for (int tm = 0; tm < 2; ++tm)
#pragma unroll
      for (int r = 0; r < 4; ++r)
        redm[wn * 64 + wm * 32 + tm * 16 + quad * 4 + r] = pm[tm][r];
  }
  __syncthreads();   // barrier 2: cross-wave rowmax

  // --- P = exp2((S - m) * INV_SQRT32 * LOG2E)  (scale folded; max commutes with scale)
  const float CEXP = INV_SQRT32 * LOG2E;
#pragma unroll
  for (int tm = 0; tm < 2; ++tm)
#pragma unroll
    for (int r = 0; r < 4; ++r) {
      int h = wm * 32 + tm * 16 + quad * 4 + r;
      float mr = fmaxf(redm[h], redm[64 + h]);
      float p0 = exp2f((accs[tm][0][r] - mr) * CEXP);
      float p1 = exp2f((accs[tm][1][r] - mr) * CEXP);
      float acc_s = p0 + p1;
      acc_s += __shfl_xor(acc_s, 1);
      acc_s += __shfl_xor(acc_s, 2);
      acc_s += __shfl_xor(acc_s, 4);
      acc_s += __shfl_xor(acc_s, 8);
      if (rt == 0) reds[wn * 64 + h] = acc_s;
      Ps[h * 72 + wn * 32 + rt]      = f2bf(p0);
      Ps[h * 72 + wn * 32 + 16 + rt] = f2bf(p1);
    }
  __syncthreads();   // barrier 3: Ps + reds visible

  // --- O = P V via MFMA: A=Ps[h][g], B=Vt[w][g], contract g
  f32x4 acco[2][2];
#pragma unroll
  for (int i = 0; i < 2; ++i)
#pragma unroll
    for (int j = 0; j < 2; ++j) acco[i][j] = (f32x4){0.f, 0.f, 0.f, 0.f};
#pragma unroll
  for (int ks = 0; ks < 2; ++ks) {
    int kk = ks * 32 + quad * 8;
    bf16x8 a0 = *(const bf16x8*)&Ps[(wm * 32 + rt) * 72 + kk];
    bf16x8 a1 = *(const bf16x8*)&Ps[(wm * 32 + 16 + rt) * 72 + kk];
    bf16x8 b0 = *(const bf16x8*)&Vt[(wn * 32 + rt) * 72 + kk];
    bf16x8 b1 = *(const bf16x8*)&Vt[(wn * 32 + 16 + rt) * 72 + kk];
    acco[0][0] = __builtin_amdgcn_mfma_f32_16x16x32_bf16(a0, b0, acco[0][0], 0, 0, 0);
    acco[0][1] = __builtin_amdgcn_mfma_f32_16x16x32_bf16(a0, b1, acco[0][1], 0, 0, 0);
    acco[1][0] = __builtin_amdgcn_mfma_f32_16x16x32_bf16(a1, b0, acco[1][0], 0, 0, 0);
    acco[1][1] = __builtin_amdgcn_mfma_f32_16x16x32_bf16(a1, b1, acco[1][1], 0, 0, 0);
  }

  float* op = out + ((size_t)(b * 256 + o)) * 4096;
#pragma unroll
  for (int tm = 0; tm < 2; ++tm) {
#pragma unroll
    for (int r = 0; r < 4; ++r) {
      int h = wm * 32 + tm * 16 + quad * 4 + r;
      float inv = 1.f / (reds[h] + reds[64 + h]);
#pragma unroll
      for (int tn = 0; tn < 2; ++tn) {
        int w = wn * 32 + tn * 16 + rt;
        op[h * 64 + w] = acco[tm][tn][r] * inv;
      }
    }
  }
}

extern "C" void kernel_launch(void* const* d_in, const int* in_sizes, int n_in,
                              void* d_out, int out_size, void* d_ws, size_t ws_size,
                              hipStream_t stream) {
  const float* x  = (const float*)d_in[0];
  const float* wq = (const float*)d_in[1];
  const float* bq = (const float*)d_in[2];
  const float* wk = (const float*)d_in[3];
  const float* bk = (const float*)d_in[4];
  const float* wv = (const float*)d_in[5];
  const float* bv = (const float*)d_in[6];
  float* out = (float*)d_out;

  // workspace layout (bytes): Wcat bf16 393216 | bias fp32 3072 | Xt bf16 33554432 | qkv bf16 100663296
  char* ws = (char*)d_ws;
  unsigned short* Wcat  = (unsigned short*)ws;
  float*          biasc = (float*)(ws + 393216);
  unsigned short* Xt    = (unsigned short*)(ws + 396288);
  unsigned short* qkv   = (unsigned short*)(ws + 396288 + 33554432);

  hipLaunchKernelGGL(pre, dim3(4288), dim3(256), 0, stream,
                     x, Xt, wq, bq, wk, bk, wv, bv, Wcat, biasc);
  hipLaunchKernelGGL(gemm_qkv, dim3(3072), dim3(256), 0, stream, Wcat, biasc, Xt, qkv);
  hipLaunchKernelGGL(attn, dim3(4096), dim3(256), 0, stream, qkv, out);
}